// Round 11
// baseline (231.647 us; speedup 1.0000x reference)
//
#include <hip/hip_runtime.h>
#include <hip/hip_fp16.h>
#include <math.h>

// EnvironmentLight IBL shade, R11.
// 2 pts/thread, NO LDS: streaming loads as aligned float2 (adjacent points share
// 24B-aligned 6-float runs per array); ALL 8 scattered dwordx4 issued in one
// batch -> 2x outstanding requests/wave vs R10 (MLP attack on gather latency).
// __launch_bounds__(256,7) caps VGPR ~73 (avoid R8's 76-VGPR occupancy cliff).
// Quad-packed textures (4xRGB9E5 / 4xhalf2), fused repack (~10us).

typedef unsigned int u32;

// ---------------- RGB9E5 ----------------
__device__ __forceinline__ u32 enc9e5(float r, float g, float b) {
    r = fminf(fmaxf(r, 0.f), 65408.f);
    g = fminf(fmaxf(g, 0.f), 65408.f);
    b = fminf(fmaxf(b, 0.f), 65408.f);
    float maxc = fmaxf(r, fmaxf(g, b));
    int e = ((__float_as_int(maxc) >> 23) & 0xff) - 127;
    int exp_p = max(e + 16, 0);
    float rd = __int_as_float((151 - exp_p) << 23);   // 2^(24-exp_p), exact
    int maxm = (int)(maxc * rd + 0.5f);
    if (maxm == 512) { exp_p += 1; rd *= 0.5f; }
    u32 rm = (u32)(r * rd + 0.5f);
    u32 gm = (u32)(g * rd + 0.5f);
    u32 bm = (u32)(b * rd + 0.5f);
    return rm | (gm << 9) | (bm << 18) | ((u32)exp_p << 27);
}

__device__ __forceinline__ void dec9e5_acc(u32 pk, float w, float& r, float& g, float& b) {
    float scale = __int_as_float((int)(((pk >> 27) & 31u) + 103u) << 23) * w;
    r += (float)(pk & 511u) * scale;
    g += (float)((pk >> 9) & 511u) * scale;
    b += (float)((pk >> 18) & 511u) * scale;
}

__device__ __forceinline__ void gather_q9(uint4 q, float tx, float ty,
                                          float& r, float& g, float& b) {
    float w00 = (1.f - tx) * (1.f - ty);
    float w01 = tx * (1.f - ty);
    float w10 = (1.f - tx) * ty;
    float w11 = tx * ty;
    r = 0.f; g = 0.f; b = 0.f;
    dec9e5_acc(q.x, w00, r, g, b);
    dec9e5_acc(q.y, w01, r, g, b);
    dec9e5_acc(q.z, w10, r, g, b);
    dec9e5_acc(q.w, w11, r, g, b);
}

__device__ __forceinline__ float srgb1(float x) {
    float p = 1.055f * __builtin_amdgcn_exp2f(
                  __builtin_amdgcn_logf(fmaxf(x, 0.0031308f)) * (1.0f / 2.4f)) - 0.055f;
    return (x <= 0.0031308f) ? (12.92f * x) : p;
}

__device__ __forceinline__ void cube_face_uv(float dx, float dy, float dz,
                                             int& face, float& u, float& v) {
    float ax = fabsf(dx), ay = fabsf(dy), az = fabsf(dz);
    bool is_x = (ax >= ay) && (ax >= az);
    bool is_y = (!is_x) && (ay >= az);
    face = is_x ? (dx > 0.f ? 0 : 1)
                : (is_y ? (dy > 0.f ? 2 : 3) : (dz > 0.f ? 4 : 5));
    float ma = fmaxf(is_x ? ax : (is_y ? ay : az), 1e-20f);
    float uu = is_x ? (dx > 0.f ? -dz : dz) : (is_y ? dx : (dz > 0.f ? dx : -dx));
    float vv = is_y ? (dy > 0.f ? dz : -dz) : -dy;
    float inv = __builtin_amdgcn_rcpf(ma);
    u = uu * inv;
    v = vv * inv;
}

// ---------------- layout constants ----------------
#define SPEC_TOTAL 2096640
#define DIF_OFF    SPEC_TOTAL
#define LUT_OFF    (SPEC_TOTAL + 1536)
#define ALL_QUADS  (SPEC_TOTAL + 1536 + 65536)

// ---------------- fused repack kernel ----------------
__global__ __launch_bounds__(256)
void repack_all(const float* __restrict__ s0, const float* __restrict__ s1,
                const float* __restrict__ s2, const float* __restrict__ s3,
                const float* __restrict__ s4, const float* __restrict__ s5,
                const float* __restrict__ diffuse_map,
                const float2* __restrict__ lut,
                uint4* __restrict__ dst)
{
    int i = blockIdx.x * blockDim.x + threadIdx.x;
    if (i >= ALL_QUADS) return;

    if (i >= LUT_OFF) {
        int k = i - LUT_OFF;
        int y = k >> 8, x = k & 255;
        int x1 = min(x + 1, 255), y1 = min(y + 1, 255);
        float2 c00 = lut[(y << 8) + x],  c01 = lut[(y << 8) + x1];
        float2 c10 = lut[(y1 << 8) + x], c11 = lut[(y1 << 8) + x1];
        __half2 h00 = __floats2half2_rn(c00.x, c00.y);
        __half2 h01 = __floats2half2_rn(c01.x, c01.y);
        __half2 h10 = __floats2half2_rn(c10.x, c10.y);
        __half2 h11 = __floats2half2_rn(c11.x, c11.y);
        uint4 q;
        q.x = *reinterpret_cast<u32*>(&h00);
        q.y = *reinterpret_cast<u32*>(&h01);
        q.z = *reinterpret_cast<u32*>(&h10);
        q.w = *reinterpret_cast<u32*>(&h11);
        dst[i] = q;
        return;
    }

    const float* src;
    int lr, local;
    if (i >= DIF_OFF)       { src = diffuse_map; lr = 4; local = i - DIF_OFF; }
    else if (i < 1572864)   { src = s0; lr = 9; local = i; }
    else if (i < 1966080)   { src = s1; lr = 8; local = i - 1572864; }
    else if (i < 2064384)   { src = s2; lr = 7; local = i - 1966080; }
    else if (i < 2088960)   { src = s3; lr = 6; local = i - 2064384; }
    else if (i < 2095104)   { src = s4; lr = 5; local = i - 2088960; }
    else                    { src = s5; lr = 4; local = i - 2095104; }

    int W = 1 << lr;
    int face = local >> (2 * lr);
    int rem = local & (W * W - 1);
    int y = rem >> lr, x = rem & (W - 1);
    int x1 = min(x + 1, W - 1), y1 = min(y + 1, W - 1);
    int base = face << (2 * lr);
    int i00 = 3 * (base + (y << lr) + x);
    int i01 = 3 * (base + (y << lr) + x1);
    int i10 = 3 * (base + (y1 << lr) + x);
    int i11 = 3 * (base + (y1 << lr) + x1);
    uint4 q;
    q.x = enc9e5(src[i00], src[i00 + 1], src[i00 + 2]);
    q.y = enc9e5(src[i01], src[i01 + 1], src[i01 + 2]);
    q.z = enc9e5(src[i10], src[i10 + 1], src[i10 + 2]);
    q.w = enc9e5(src[i11], src[i11 + 1], src[i11 + 2]);
    dst[i] = q;
}

// ---------------- per-point address computation ----------------
struct PtAddr {
    int aOff, bOff, lutOff, dOff;                // absolute quad indices into q
    float atx, aty, btx, bty, ltx, lty, dtx, dty, fmip;
};

__device__ __forceinline__ PtAddr pt_addr(float vx, float vy, float vz,
                                          float nx, float ny, float nz,
                                          float rough,
                                          float& rvdotn) {
    PtAddr P;
    float vdotn = vx * nx + vy * ny + vz * nz;
    rvdotn = vdotn;
    float rx = 2.f * vdotn * nx - vx;
    float ry = 2.f * vdotn * ny - vy;
    float rz = 2.f * vdotn * nz - vz;
    float rinv = __builtin_amdgcn_rsqf(fmaxf(rx * rx + ry * ry + rz * rz, 1e-20f));
    rx *= rinv; ry *= rinv; rz *= rinv;

    // diffuse (lr=4)
    {
        int face; float u, v;
        cube_face_uv(nx, ny, nz, face, u, v);
        float fx = (u * 0.5f + 0.5f) * 16.f - 0.5f;
        float fy = (v * 0.5f + 0.5f) * 16.f - 0.5f;
        float x0f = floorf(fx), y0f = floorf(fy);
        P.dtx = fx - x0f; P.dty = fy - y0f;
        int x0 = min(max((int)x0f, 0), 15);
        int y0 = min(max((int)y0f, 0), 15);
        P.dOff = DIF_OFF + (face << 8) + (y0 << 4) + x0;
    }

    // LUT
    {
        float NdotV = fmaxf(vdotn, 1e-4f);
        float fx = NdotV * 256.f - 0.5f;
        float fy = rough * 256.f - 0.5f;
        float x0f = floorf(fx), y0f = floorf(fy);
        P.ltx = fx - x0f; P.lty = fy - y0f;
        int x0 = min(max((int)x0f, 0), 255);
        int y0 = min(max((int)y0f, 0), 255);
        P.lutOff = LUT_OFF + (y0 << 8) + x0;
    }

    // mip selection
    const float MINR = 0.08f, MAXR = 0.5f;
    float lo = (fminf(fmaxf(rough, MINR), MAXR) - MINR) * (4.0f / (MAXR - MINR));
    float hi = (fminf(fmaxf(rough, MAXR), 1.0f) - MAXR) * (1.0f / (1.0f - MAXR)) + 4.0f;
    float lvl = fminf(fmaxf((rough < MAXR) ? lo : hi, 0.f), 5.f);
    int l0 = min(max((int)floorf(lvl), 0), 5);
    int l1 = min(l0 + 1, 5);
    P.fmip = lvl - (float)l0;

    static const int OFF[6] = {0, 1572864, 1966080, 2064384, 2088960, 2095104};
    {
        int face; float u, v;
        cube_face_uv(rx, ry, rz, face, u, v);
        int lrA = 9 - l0, lrB = 9 - l1;
        float RA = (float)(1 << lrA);
        float fxA = (u * 0.5f + 0.5f) * RA - 0.5f;
        float fyA = (v * 0.5f + 0.5f) * RA - 0.5f;
        float fxB = (l0 == l1) ? fxA : (fxA + 0.5f) * 0.5f - 0.5f;
        float fyB = (l0 == l1) ? fyA : (fyA + 0.5f) * 0.5f - 0.5f;

        float x0fA = floorf(fxA), y0fA = floorf(fyA);
        P.atx = fxA - x0fA; P.aty = fyA - y0fA;
        int WA = 1 << lrA;
        int x0A = min(max((int)x0fA, 0), WA - 1);
        int y0A = min(max((int)y0fA, 0), WA - 1);
        P.aOff = OFF[l0] + (face << (2 * lrA)) + (y0A << lrA) + x0A;

        float x0fB = floorf(fxB), y0fB = floorf(fyB);
        P.btx = fxB - x0fB; P.bty = fyB - y0fB;
        int WB = 1 << lrB;
        int x0B = min(max((int)x0fB, 0), WB - 1);
        int y0B = min(max((int)y0fB, 0), WB - 1);
        P.bOff = OFF[l1] + (face << (2 * lrB)) + (y0B << lrB) + x0B;
    }
    return P;
}

__device__ __forceinline__ void pt_shade(const PtAddr& P,
                                         uint4 qA, uint4 qB, uint4 lq, uint4 dq,
                                         float kdx, float kdy, float kdz,
                                         float ks0, float metallic, float occ,
                                         float& o0, float& o1, float& o2) {
    float ar, ag, ab_, br, bg, bb;
    gather_q9(qA, P.atx, P.aty, ar, ag, ab_);
    gather_q9(qB, P.btx, P.bty, br, bg, bb);

    __half2 h00 = *reinterpret_cast<const __half2*>(&lq.x);
    __half2 h01 = *reinterpret_cast<const __half2*>(&lq.y);
    __half2 h10 = *reinterpret_cast<const __half2*>(&lq.z);
    __half2 h11 = *reinterpret_cast<const __half2*>(&lq.w);
    float2 c00 = __half22float2(h00), c01 = __half22float2(h01);
    float2 c10 = __half22float2(h10), c11 = __half22float2(h11);
    float lw00 = (1.f - P.ltx) * (1.f - P.lty);
    float lw01 = P.ltx * (1.f - P.lty);
    float lw10 = (1.f - P.ltx) * P.lty;
    float lw11 = P.ltx * P.lty;
    float fg0 = c00.x * lw00 + c01.x * lw01 + c10.x * lw10 + c11.x * lw11;
    float fg1 = c00.y * lw00 + c01.y * lw01 + c10.y * lw10 + c11.y * lw11;

    float dfr, dfg, dfb;
    gather_q9(dq, P.dtx, P.dty, dfr, dfg, dfb);
    dfr = fmaxf(dfr, 0.f); dfg = fmaxf(dfg, 0.f); dfb = fmaxf(dfb, 0.f);

    float spr = fmaxf(ar * (1.f - P.fmip) + br * P.fmip, 0.f);
    float spg = fmaxf(ag * (1.f - P.fmip) + bg * P.fmip, 0.f);
    float spb = fmaxf(ab_ * (1.f - P.fmip) + bb * P.fmip, 0.f);

    float m = metallic;
    float scx = (1.f - m) * 0.04f + kdx * m;
    float scy = (1.f - m) * 0.04f + kdy * m;
    float scz = (1.f - m) * 0.04f + kdz * m;
    float kds = 1.f - ks0;
    float om = 1.f - occ;
    float shx = dfr * kdx * (1.f - m) * kds + spr * (scx * fg0 + fg1) * om;
    float shy = dfg * kdy * (1.f - m) * kds + spg * (scy * fg0 + fg1) * om;
    float shz = dfb * kdz * (1.f - m) * kds + spb * (scz * fg0 + fg1) * om;

    o0 = srgb1(fminf(fmaxf(shx, 0.f), 1.f));
    o1 = srgb1(fminf(fmaxf(shy, 0.f), 1.f));
    o2 = srgb1(fminf(fmaxf(shz, 0.f), 1.f));
}

// ---------------- main kernel: 2 pts/thread ----------------
__global__ __launch_bounds__(256, 7)
void envlight_p2(const float2* __restrict__ vd2,
                 const float2* __restrict__ nm2,
                 const float2* __restrict__ kd2,
                 const float2* __restrict__ ks2,
                 const float2* __restrict__ oc2,
                 const uint4* __restrict__ q,
                 float2* __restrict__ out2, int nt, int n)
{
    int t = blockIdx.x * blockDim.x + threadIdx.x;
    if (t >= nt) return;
    // points 2t, 2t+1. n is even in this harness (2^21); guard kept for safety.

    // streaming: 6 floats per array for the pair = 3 aligned float2 loads each
    float2 va = vd2[3 * t], vb = vd2[3 * t + 1], vc = vd2[3 * t + 2];
    float2 na = nm2[3 * t], nb = nm2[3 * t + 1], nc = nm2[3 * t + 2];
    float2 qa = ks2[3 * t], qb = ks2[3 * t + 1], qc = ks2[3 * t + 2];

    float dummy0, dummy1;
    PtAddr P0 = pt_addr(va.x, va.y, vb.x, na.x, na.y, nb.x, qa.y, dummy0);
    PtAddr P1 = pt_addr(vb.y, vc.x, vc.y, nb.y, nc.x, nc.y, qc.x, dummy1);

    // ---- issue ALL 8 scattered dwordx4 loads in one batch ----
    uint4 qA0 = q[P0.aOff];
    uint4 qB0 = q[P0.bOff];
    uint4 lq0 = q[P0.lutOff];
    uint4 dq0 = q[P0.dOff];
    uint4 qA1 = q[P1.aOff];
    uint4 qB1 = q[P1.bOff];
    uint4 lq1 = q[P1.lutOff];
    uint4 dq1 = q[P1.dOff];

    // independent streaming loads overlap the scattered latency
    float2 ka = kd2[3 * t], kb = kd2[3 * t + 1], kc = kd2[3 * t + 2];
    float2 oc = oc2[t];

    float r0, g0, b0, r1, g1, b1;
    pt_shade(P0, qA0, qB0, lq0, dq0, ka.x, ka.y, kb.x, qa.x, qb.x, oc.x, r0, g0, b0);
    pt_shade(P1, qA1, qB1, lq1, dq1, kb.y, kc.x, kc.y, qb.y, qc.y, oc.y, r1, g1, b1);

    out2[3 * t]     = make_float2(r0, g0);
    out2[3 * t + 1] = make_float2(b0, r1);
    out2[3 * t + 2] = make_float2(g1, b1);
}

// ---------------- raw-float fallback (ws too small; shouldn't trigger) ----------------
__global__ __launch_bounds__(256)
void envlight_raw(const float* __restrict__ view_dir,
                  const float* __restrict__ normal,
                  const float* __restrict__ kd,
                  const float* __restrict__ ks,
                  const float* __restrict__ reflect_occ,
                  const float* __restrict__ diffuse_map,
                  const float* __restrict__ s0, const float* __restrict__ s1,
                  const float* __restrict__ s2, const float* __restrict__ s3,
                  const float* __restrict__ s4, const float* __restrict__ s5,
                  const float* __restrict__ fg_lut,
                  float* __restrict__ out, int n)
{
    int i = blockIdx.x * blockDim.x + threadIdx.x;
    if (i >= n) return;

    float vx = view_dir[3 * i], vy = view_dir[3 * i + 1], vz = view_dir[3 * i + 2];
    float nx = normal[3 * i],  ny = normal[3 * i + 1],  nz = normal[3 * i + 2];
    float kdx = kd[3 * i], kdy = kd[3 * i + 1], kdz = kd[3 * i + 2];
    float ks0 = ks[3 * i], rough = ks[3 * i + 1], metallic = ks[3 * i + 2];
    float occ = reflect_occ[i];

    float vdotn = vx * nx + vy * ny + vz * nz;
    float rx = 2.f * vdotn * nx - vx;
    float ry = 2.f * vdotn * ny - vy;
    float rz = 2.f * vdotn * nz - vz;
    float rinv = __builtin_amdgcn_rsqf(fmaxf(rx * rx + ry * ry + rz * rz, 1e-20f));
    rx *= rinv; ry *= rinv; rz *= rinv;

    const float* mips[6] = {s0, s1, s2, s3, s4, s5};

    const float MINR = 0.08f, MAXR = 0.5f;
    float lo = (fminf(fmaxf(rough, MINR), MAXR) - MINR) * (4.0f / (MAXR - MINR));
    float hi = (fminf(fmaxf(rough, MAXR), 1.0f) - MAXR) * (1.0f / (1.0f - MAXR)) + 4.0f;
    float lvl = fminf(fmaxf((rough < MAXR) ? lo : hi, 0.f), 5.f);
    int l0 = min(max((int)floorf(lvl), 0), 5);
    int l1 = min(l0 + 1, 5);
    float f = lvl - (float)l0;

    float acc[3][3];
    float dirs[3][3] = {{nx, ny, nz}, {rx, ry, rz}, {rx, ry, rz}};
    int lrs[3] = {4, 9 - l0, 9 - l1};
    const float* texs[3] = {diffuse_map, mips[l0], mips[l1]};
    for (int s = 0; s < 3; ++s) {
        int face; float u, v;
        cube_face_uv(dirs[s][0], dirs[s][1], dirs[s][2], face, u, v);
        int lr = lrs[s], W = 1 << lr;
        float fx = (u * 0.5f + 0.5f) * (float)W - 0.5f;
        float fy = (v * 0.5f + 0.5f) * (float)W - 0.5f;
        float x0f = floorf(fx), y0f = floorf(fy);
        float tx = fx - x0f, ty = fy - y0f;
        int x0 = min(max((int)x0f, 0), W - 1);
        int x1 = min(x0 + 1, W - 1);
        int y0 = min(max((int)y0f, 0), W - 1);
        int y1 = min(y0 + 1, W - 1);
        int base = face << (2 * lr);
        const float* tt = texs[s];
        const float* p00 = tt + 3 * (base + (y0 << lr) + x0);
        const float* p01 = tt + 3 * (base + (y0 << lr) + x1);
        const float* p10 = tt + 3 * (base + (y1 << lr) + x0);
        const float* p11 = tt + 3 * (base + (y1 << lr) + x1);
        float w00 = (1.f - tx) * (1.f - ty), w01 = tx * (1.f - ty);
        float w10 = (1.f - tx) * ty, w11 = tx * ty;
        for (int c = 0; c < 3; ++c)
            acc[s][c] = p00[c] * w00 + p01[c] * w01 + p10[c] * w10 + p11[c] * w11;
    }

    float NdotV = fmaxf(vdotn, 1e-4f);
    float fx = NdotV * 256.f - 0.5f, fy = rough * 256.f - 0.5f;
    float x0f = floorf(fx), y0f = floorf(fy);
    float tx = fx - x0f, ty = fy - y0f;
    int x0 = min(max((int)x0f, 0), 255);
    int x1 = min(x0 + 1, 255);
    int y0 = min(max((int)y0f, 0), 255);
    int y1 = min(y0 + 1, 255);
    const float2* lut2 = (const float2*)fg_lut;
    float2 c00 = lut2[(y0 << 8) + x0], c01 = lut2[(y0 << 8) + x1];
    float2 c10 = lut2[(y1 << 8) + x0], c11 = lut2[(y1 << 8) + x1];
    float w00 = (1.f - tx) * (1.f - ty), w01 = tx * (1.f - ty);
    float w10 = (1.f - tx) * ty, w11 = tx * ty;
    float fg0 = c00.x * w00 + c01.x * w01 + c10.x * w10 + c11.x * w11;
    float fg1 = c00.y * w00 + c01.y * w01 + c10.y * w10 + c11.y * w11;

    float dfr = fmaxf(acc[0][0], 0.f), dfg = fmaxf(acc[0][1], 0.f), dfb = fmaxf(acc[0][2], 0.f);
    float spr = fmaxf(acc[1][0] * (1.f - f) + acc[2][0] * f, 0.f);
    float spg = fmaxf(acc[1][1] * (1.f - f) + acc[2][1] * f, 0.f);
    float spb = fmaxf(acc[1][2] * (1.f - f) + acc[2][2] * f, 0.f);

    float m = metallic;
    float scx = (1.f - m) * 0.04f + kdx * m;
    float scy = (1.f - m) * 0.04f + kdy * m;
    float scz = (1.f - m) * 0.04f + kdz * m;
    float kds = 1.f - ks0;
    float om = 1.f - occ;
    float shx = dfr * kdx * (1.f - m) * kds + spr * (scx * fg0 + fg1) * om;
    float shy = dfg * kdy * (1.f - m) * kds + spg * (scy * fg0 + fg1) * om;
    float shz = dfb * kdz * (1.f - m) * kds + spb * (scz * fg0 + fg1) * om;

    out[3 * i + 0] = srgb1(fminf(fmaxf(shx, 0.f), 1.f));
    out[3 * i + 1] = srgb1(fminf(fmaxf(shy, 0.f), 1.f));
    out[3 * i + 2] = srgb1(fminf(fmaxf(shz, 0.f), 1.f));
}

extern "C" void kernel_launch(void* const* d_in, const int* in_sizes, int n_in,
                              void* d_out, int out_size, void* d_ws, size_t ws_size,
                              hipStream_t stream) {
    const float* view_dir    = (const float*)d_in[0];
    const float* normal      = (const float*)d_in[1];
    const float* kd          = (const float*)d_in[2];
    const float* ks          = (const float*)d_in[3];
    const float* reflect_occ = (const float*)d_in[4];
    const float* diffuse_map = (const float*)d_in[5];
    const float* s0          = (const float*)d_in[6];
    const float* s1          = (const float*)d_in[7];
    const float* s2          = (const float*)d_in[8];
    const float* s3          = (const float*)d_in[9];
    const float* s4          = (const float*)d_in[10];
    const float* s5          = (const float*)d_in[11];
    const float* fg_lut      = (const float*)d_in[12];
    float* out = (float*)d_out;

    int n = in_sizes[0] / 3;
    const size_t NEED_Q = (size_t)ALL_QUADS * 16;   // ~34.6 MB

    if (ws_size >= NEED_Q && (n & 1) == 0) {
        uint4* q = (uint4*)d_ws;
        repack_all<<<(ALL_QUADS + 255) / 256, 256, 0, stream>>>(
            s0, s1, s2, s3, s4, s5, diffuse_map, (const float2*)fg_lut, q);
        int nt = n / 2;
        envlight_p2<<<(nt + 255) / 256, 256, 0, stream>>>(
            (const float2*)view_dir, (const float2*)normal,
            (const float2*)kd, (const float2*)ks,
            (const float2*)reflect_occ, q, (float2*)out, nt, n);
    } else {
        envlight_raw<<<(n + 255) / 256, 256, 0, stream>>>(
            view_dir, normal, kd, ks, reflect_occ, diffuse_map,
            s0, s1, s2, s3, s4, s5, fg_lut, out, n);
    }
}